// Round 6
// baseline (164.601 us; speedup 1.0000x reference)
//
#include <hip/hip_runtime.h>
#include <hip/hip_bf16.h>

// Problem constants (fixed by the reference setup)
#define N_ROWS   500000
#define NR1      25        // nr + 1
#define NGROUPS  20000     // N_ROWS / NR1
#define KCTX     20        // K context indices
#define H        128
#define NODES    10000
#define IDX_COLS 23        // 3 + K

typedef __attribute__((ext_vector_type(8))) short short8;   // 8 bf16 = 4 VGPRs
typedef __attribute__((ext_vector_type(4))) float f32x4;    // MFMA C/D

// pack two floats -> two bf16 (RNE) as a 32-bit word
__device__ __forceinline__ unsigned pkbf(float lo, float hi) {
  __hip_bfloat162 h = __float22bfloat162_rn(make_float2(lo, hi));
  union { __hip_bfloat162 h; unsigned u; } c; c.h = h;
  return c.u;
}
// bf16-pair word -> two floats (1 VALU each)
__device__ __forceinline__ float lo2f(unsigned u) {
  union { unsigned u; float f; } c; c.u = u << 16; return c.f;
}
__device__ __forceinline__ float hi2f(unsigned u) {
  union { unsigned u; float f; } c; c.u = u & 0xffff0000u; return c.f;
}

// ---------------------------------------------------------------------------
// Kernel PRE (v10): ONE kernel, all blocks independent (R5 post-mortem: the
//  k_precompute -> k_ctx serial chain cost ~90-100 us; means over U forced
//  the dependency. Means taken directly over x removes it.)
//   blocks [0,313)      : FAT Pg blocks — 64 groups each: means(x) -> LDS bf16
//                         -> GEMM vs W13(LDS) -> Pg bf16 (b1 folded)
//   blocks [313,941)    : P1 = x @ W10.T, P2 = x @ W11.T (157 tbase x 2 ch)
//   blocks [941,1098)   : idx2 pack (strided indices stream read ONCE here;
//                         k_main reads the 4 MB sequential table instead of
//                         the 92B-stride stream = ~65 MB of its FETCH)
//   block  1098         : w2f pack (W2 -> bf16 MFMA-fragment order)
// ---------------------------------------------------------------------------
#define PN 64
#define PBLK      ((NODES + PN - 1) / PN)        // 157
#define B_PG_END  ((NGROUPS + 63) / 64)          // 313 fat Pg blocks
#define B_P12     B_PG_END                       // 313
#define B_IDXP    (B_P12 + 4 * PBLK)             // 941
#define B_W2FP    (B_IDXP + PBLK)                // 1098
#define PRE_BLOCKS (B_W2FP + 1)                  // 1099

__global__ __launch_bounds__(256) void k_pre(
    const int* __restrict__ indices, const float* __restrict__ x,
    const float* __restrict__ W1, const float* __restrict__ b1,
    const float* __restrict__ W2,
    unsigned short* __restrict__ Pb, unsigned short* __restrict__ Pgb,
    unsigned short* __restrict__ w2f, int2* __restrict__ idx2) {
  __shared__ __align__(16) short lds_all[24576];   // 48 KB, aliased per path

  const int tid = threadIdx.x;
  const int bid = blockIdx.x;
  const int lane = tid & 63;
  const int wvid = tid >> 6;
  const int col  = lane & 15;
  const int quad = lane >> 4;

  if (bid >= B_IDXP) {
    if (bid == B_W2FP) {
      // pack W2 into fragment order: frag fi=(kt*4+ct), lane -> 8 bf16 of
      // W2[ct*16+col][kt*32+quad*8 .. +8]. 16 KB; k_main stages it to LDS.
#pragma unroll
      for (int i = 0; i < 4; ++i) {
        const int fi = i * 4 + wvid;         // 0..15
        const int kt = fi >> 2, ct = fi & 3;
        const float* __restrict__ src =
            W2 + (size_t)(ct * 16 + col) * H + kt * 32 + quad * 8;
        const float4 v0 = *(const float4*)src;
        const float4 v1 = *(const float4*)(src + 4);
        union { short8 v; unsigned u[4]; } pk;
        pk.u[0] = pkbf(v0.x, v0.y);
        pk.u[1] = pkbf(v0.z, v0.w);
        pk.u[2] = pkbf(v1.x, v1.y);
        pk.u[3] = pkbf(v1.z, v1.w);
        *(short8*)(w2f + (size_t)(fi * 64 + lane) * 8) = pk.v;
      }
    } else {
      // idx2 pack: coalesced-ish one-time read of the indices stream
      const int stride = PBLK * 256;
      for (int r = (bid - B_IDXP) * 256 + tid; r < N_ROWS; r += stride)
        idx2[r] = make_int2(indices[(size_t)r * IDX_COLS + 0],
                            indices[(size_t)r * IDX_COLS + 1]);
    }
    return;
  }

  if (bid < B_PG_END) {
    // ---- FAT Pg block: 64 groups, self-contained (no cross-kernel dep) ----
    short* w13  = lds_all;             // [128][128] bf16, swizzled (32 KB)
    short* mlds = lds_all + 16384;     // [64][128] bf16 means, swizzled (16 KB)
    const int gbase = bid * 64;

    // stage W13 (W1 cols [2H,3H)) -> LDS bf16, XOR-swizzled
#pragma unroll
    for (int it = 0; it < 16; ++it) {
      const int f  = it * 256 + tid;   // 0..4095 float4 index
      const int j  = f >> 5;           // 0..127 row
      const int q4 = f & 31;
      const float4 v = *(const float4*)(W1 + (size_t)j * (3 * H) + 2 * H + q4 * 4);
      const int sidx = j * 128 + (((q4 >> 1) ^ (j & 7)) << 3) + (q4 & 1) * 4;
      *(unsigned*)&w13[sidx]     = pkbf(v.x, v.y);
      *(unsigned*)&w13[sidx + 2] = pkbf(v.z, v.w);
    }

    // means over x: wave wv owns groups [gbase+wv*16, +16), 2 in flight
    const int jj = lane * 2;
#pragma unroll
    for (int it = 0; it < 8; ++it) {
      const int ga = gbase + wvid * 16 + it;
      const int gb = ga + 8;
      const int gac = (ga < NGROUPS) ? ga : (NGROUPS - 1);
      const int gbc = (gb < NGROUPS) ? gb : (NGROUPS - 1);
      const int* __restrict__ ra = indices + (size_t)gac * NR1 * IDX_COLS + 3;
      const int* __restrict__ rb = indices + (size_t)gbc * NR1 * IDX_COLS + 3;
      float a0 = 0.f, a1 = 0.f, c0 = 0.f, c1 = 0.f;
      int ca = 0, cb = 0;
#pragma unroll
      for (int c = 0; c < KCTX; ++c) {
        const int ia = ra[c], ib = rb[c];
        const float2 va = *(const float2*)(x + (size_t)ia * H + jj);
        const float2 vb = *(const float2*)(x + (size_t)ib * H + jj);
        a0 += va.x; a1 += va.y; c0 += vb.x; c1 += vb.y;
        ca += (ia > 0) ? 1 : 0; cb += (ib > 0) ? 1 : 0;
      }
      const float rna = 1.f / (float)((ca > 1) ? ca : 1);
      const float rnb = 1.f / (float)((cb > 1) ? cb : 1);
      {
        const int row = wvid * 16 + it;
        const int sb = row * 128 + (((lane >> 2) ^ (row & 7)) << 3) + (lane & 3) * 2;
        *(unsigned*)&mlds[sb] = pkbf(a0 * rna, a1 * rna);
      }
      {
        const int row = wvid * 16 + it + 8;
        const int sb = row * 128 + (((lane >> 2) ^ (row & 7)) << 3) + (lane & 3) * 2;
        *(unsigned*)&mlds[sb] = pkbf(c0 * rnb, c1 * rnb);
      }
    }
    __syncthreads();

    // GEMM: Pg[g][:] = mean[g] @ W13.T (+b1), 16 group-rows per wave
    short8 Af[4];
    const int arow = wvid * 16 + col;
#pragma unroll
    for (int kt = 0; kt < 4; ++kt)
      Af[kt] = *(const short8*)
          &mlds[arow * 128 + (((kt * 4 + quad) ^ (arow & 7)) << 3)];

    f32x4 acc[8];
#pragma unroll
    for (int ct = 0; ct < 8; ++ct) acc[ct] = (f32x4)(0.f);
#pragma unroll
    for (int kt = 0; kt < 4; ++kt) {
#pragma unroll
      for (int ct = 0; ct < 8; ++ct) {
        const int brow = ct * 16 + col;
        const short8 Bf = *(const short8*)
            &w13[brow * 128 + (((kt * 4 + quad) ^ (brow & 7)) << 3)];
        acc[ct] = __builtin_amdgcn_mfma_f32_16x16x32_bf16(Af[kt], Bf, acc[ct], 0, 0, 0);
      }
    }
    float b1v[8];
#pragma unroll
    for (int ct = 0; ct < 8; ++ct) b1v[ct] = b1[ct * 16 + col];
#pragma unroll
    for (int reg = 0; reg < 4; ++reg) {
      const int g2 = gbase + wvid * 16 + quad * 4 + reg;
      if (g2 < NGROUPS) {
#pragma unroll
        for (int ct = 0; ct < 8; ++ct) {
          union { unsigned u; unsigned short s[2]; } c;
          c.u = pkbf(acc[ct][reg] + b1v[ct], 0.f);
          Pgb[(size_t)g2 * H + ct * 16 + col] = c.s[0];
        }
      }
    }
    return;
  }

  // ---- P1/P2 GEMM slices ----
  {
    short* wlds = lds_all;                   // 16 KB used
    const int local = bid - B_P12;
    const int m   = local / (2 * PBLK);      // 0 or 1
    const int sub = local - m * (2 * PBLK);
    const int tbase = (sub >> 1) * PN;
    const int ch    = sub & 1;

#pragma unroll
    for (int it = 0; it < 8; ++it) {
      const int f  = it * 256 + tid;
      const int j  = f >> 5;
      const int q4 = f & 31;
      const float4 v =
          *(const float4*)(W1 + (size_t)(ch * 64 + j) * (3 * H) + m * H + q4 * 4);
      const int sidx = j * 128 + (((q4 >> 1) ^ (j & 7)) << 3) + (q4 & 1) * 4;
      *(unsigned*)&wlds[sidx]     = pkbf(v.x, v.y);
      *(unsigned*)&wlds[sidx + 2] = pkbf(v.z, v.w);
    }
    __syncthreads();

    int node = tbase + wvid * 16 + col;
    if (node > NODES - 1) node = NODES - 1;
    const float4* __restrict__ xr = (const float4*)(x + (size_t)node * H);
    short8 Af[4];
#pragma unroll
    for (int kt = 0; kt < 4; ++kt) {
      const int f4 = kt * 8 + quad * 2;
      const float4 v0 = xr[f4], v1 = xr[f4 + 1];
      union { short8 v; unsigned u[4]; } pk;
      pk.u[0] = pkbf(v0.x, v0.y);
      pk.u[1] = pkbf(v0.z, v0.w);
      pk.u[2] = pkbf(v1.x, v1.y);
      pk.u[3] = pkbf(v1.z, v1.w);
      Af[kt] = pk.v;
    }

    f32x4 acc[4];
#pragma unroll
    for (int ct = 0; ct < 4; ++ct) acc[ct] = (f32x4)(0.f);
#pragma unroll
    for (int kt = 0; kt < 4; ++kt) {
#pragma unroll
      for (int ct = 0; ct < 4; ++ct) {
        const int brow = ct * 16 + col;
        const short8 Bf = *(const short8*)
            &wlds[brow * 128 + (((kt * 4 + quad) ^ (brow & 7)) << 3)];
        acc[ct] = __builtin_amdgcn_mfma_f32_16x16x32_bf16(Af[kt], Bf, acc[ct], 0, 0, 0);
      }
    }

    unsigned short* __restrict__ Pm = Pb + (size_t)m * NODES * H;
#pragma unroll
    for (int reg = 0; reg < 4; ++reg) {
      const int n = tbase + wvid * 16 + quad * 4 + reg;
      if (n < NODES) {
#pragma unroll
        for (int ct = 0; ct < 4; ++ct) {
          union { unsigned u; unsigned short s[2]; } c;
          c.u = pkbf(acc[ct][reg], 0.f);
          Pm[(size_t)n * H + ch * 64 + ct * 16 + col] = c.s[0];
        }
      }
    }
  }
}

// ---------------------------------------------------------------------------
// Kernel C (v17): wave-independent, 32 rows/wave; v16 + idx2 table.
//  R5 post-mortem: FETCH 78 MB ≈ 67 MB of stride-92B indices stream (8 B
//  used per 128 B fetched). idx2 (8 B/row, sequential, 4 MB) removes it.
// ---------------------------------------------------------------------------
#define RPW 32       // rows per wave
__global__ __launch_bounds__(256, 4) void k_main(
    const int2* __restrict__ idx2,
    const unsigned short* __restrict__ P1b, const unsigned short* __restrict__ P2b,
    const unsigned short* __restrict__ Pgb, const unsigned short* __restrict__ w2f,
    const float* __restrict__ b2, const float* __restrict__ W3,
    const float* __restrict__ b3, float* __restrict__ out) {
  __shared__ __align__(16) short w2s[16 * 64 * 8];   // 16 KB, fragment-ordered

  const int tid  = threadIdx.x;
  const int lane = tid & 63;
  const int wv   = tid >> 6;
  const int col  = lane & 15;
  const int quad = lane >> 4;

  // ---- stage w2f -> LDS (64 B/thread, dense) + barrier at block start ----
  {
    const short8* __restrict__ src = (const short8*)w2f;
    short8* dst = (short8*)w2s;
#pragma unroll
    for (int i = 0; i < 4; ++i) dst[i * 256 + tid] = src[i * 256 + tid];
  }
  __syncthreads();

  const int Rw = (blockIdx.x * 4 + wv) * RPW;        // this wave's 32 rows
  const int r0 = Rw + col, r1 = Rw + 16 + col;
  const int rc0 = (r0 < N_ROWS) ? r0 : (N_ROWS - 1);
  const int rc1 = (r1 < N_ROWS) ? r1 : (N_ROWS - 1);
  const int g0 = rc0 / NR1, g1 = rc1 / NR1;          // magic-mul division

  // ---- ctx gathers (no load dependency -> issue first) ----
  const short8* __restrict__ pc0 = (const short8*)(Pgb + (size_t)g0 * H);
  const short8* __restrict__ pc1 = (const short8*)(Pgb + (size_t)g1 * H);
  short8 uc0[4], uc1[4];
#pragma unroll
  for (int kt = 0; kt < 4; ++kt) {
    uc0[kt] = pc0[kt * 4 + quad];
    uc1[kt] = pc1[kt * 4 + quad];
  }

  // ---- row indices from packed table (8 B/row, sequential, L2/L3-hot) ----
  const int2 iA = idx2[rc0];
  const int2 iB = idx2[rc1];

  // ---- P1/P2 gathers, both groups, all in flight ----
  const short8* __restrict__ pa0 = (const short8*)(P1b + (size_t)iA.x * H);
  const short8* __restrict__ pb0 = (const short8*)(P2b + (size_t)iA.y * H);
  const short8* __restrict__ pa1 = (const short8*)(P1b + (size_t)iB.x * H);
  const short8* __restrict__ pb1 = (const short8*)(P2b + (size_t)iB.y * H);
  short8 ua0[4], ub0[4], ua1[4], ub1[4];
#pragma unroll
  for (int kt = 0; kt < 4; ++kt) {
    ua0[kt] = pa0[kt * 4 + quad];
    ub0[kt] = pb0[kt * 4 + quad];
    ua1[kt] = pa1[kt * 4 + quad];
    ub1[kt] = pb1[kt * 4 + quad];
  }
  __builtin_amdgcn_sched_barrier(0);   // pin: all gathers issued before use

  // ---- epilogue constants (L1-hot) ----
  float b2v[4], w3v[4];
#pragma unroll
  for (int ct = 0; ct < 4; ++ct) {
    b2v[ct] = b2[ct * 16 + col];
    w3v[ct] = W3[ct * 16 + col];
  }
  const float bias3 = b3[0];

  // ---- A-build both groups: relu(P1 + P2 + ctx) -> bf16 fragments ----
  short8 A0[4], A1[4];
#pragma unroll
  for (int kt = 0; kt < 4; ++kt) {
    union { short8 v; unsigned u[4]; } va, vb, vc;
    va.v = ua0[kt]; vb.v = ub0[kt]; vc.v = uc0[kt];
    union { short8 v; unsigned u[4]; } pk;
#pragma unroll
    for (int w = 0; w < 4; ++w) {
      const float hl = fmaxf(lo2f(va.u[w]) + lo2f(vb.u[w]) + lo2f(vc.u[w]), 0.f);
      const float hh = fmaxf(hi2f(va.u[w]) + hi2f(vb.u[w]) + hi2f(vc.u[w]), 0.f);
      pk.u[w] = pkbf(hl, hh);
    }
    A0[kt] = pk.v;
  }
#pragma unroll
  for (int kt = 0; kt < 4; ++kt) {
    union { short8 v; unsigned u[4]; } va, vb, vc;
    va.v = ua1[kt]; vb.v = ub1[kt]; vc.v = uc1[kt];
    union { short8 v; unsigned u[4]; } pk;
#pragma unroll
    for (int w = 0; w < 4; ++w) {
      const float hl = fmaxf(lo2f(va.u[w]) + lo2f(vb.u[w]) + lo2f(vc.u[w]), 0.f);
      const float hh = fmaxf(hi2f(va.u[w]) + hi2f(vb.u[w]) + hi2f(vc.u[w]), 0.f);
      pk.u[w] = pkbf(hl, hh);
    }
    A1[kt] = pk.v;
  }

  // ---- MFMA layer 2: shared B-frags from LDS, both groups ----
  f32x4 acc0[4], acc1[4];
#pragma unroll
  for (int ct = 0; ct < 4; ++ct) { acc0[ct] = (f32x4)(0.f); acc1[ct] = (f32x4)(0.f); }
#pragma unroll
  for (int kt = 0; kt < 4; ++kt) {
#pragma unroll
    for (int ct = 0; ct < 4; ++ct) {
      const short8 Bf = *(const short8*)&w2s[((kt * 4 + ct) * 64 + lane) * 8];
      acc0[ct] = __builtin_amdgcn_mfma_f32_16x16x32_bf16(A0[kt], Bf, acc0[ct], 0, 0, 0);
      acc1[ct] = __builtin_amdgcn_mfma_f32_16x16x32_bf16(A1[kt], Bf, acc1[ct], 0, 0, 0);
    }
  }

  // ---- epilogue: relu(acc+b2) @ W3 + b3, reduce over 16 cols, store ----
#pragma unroll
  for (int grp = 0; grp < 2; ++grp) {
#pragma unroll
    for (int reg = 0; reg < 4; ++reg) {
      float s = 0.f;
#pragma unroll
      for (int ct = 0; ct < 4; ++ct) {
        const float a = (grp == 0) ? acc0[ct][reg] : acc1[ct][reg];
        s += fmaxf(a + b2v[ct], 0.f) * w3v[ct];
      }
      s += __shfl_xor(s, 1);
      s += __shfl_xor(s, 2);
      s += __shfl_xor(s, 4);
      s += __shfl_xor(s, 8);
      if (col == 0) {
        const int row = Rw + grp * 16 + quad * 4 + reg;   // C row = quad*4+reg
        if (row < N_ROWS) out[row] = s + bias3;
      }
    }
  }
}

// ---------------------------------------------------------------------------
extern "C" void kernel_launch(void* const* d_in, const int* in_sizes, int n_in,
                              void* d_out, int out_size, void* d_ws, size_t ws_size,
                              hipStream_t stream) {
  const int*   indices = (const int*)  d_in[0];
  // d_in[1] = nr (scalar, fixed at 24)
  const float* x  = (const float*)d_in[2];
  const float* W1 = (const float*)d_in[3];
  const float* b1 = (const float*)d_in[4];
  const float* W2 = (const float*)d_in[5];
  const float* b2 = (const float*)d_in[6];
  const float* W3 = (const float*)d_in[7];
  const float* b3 = (const float*)d_in[8];
  float* out = (float*)d_out;

  // Workspace: P1|P2 (bf16, 2.56 MB each) | Pg (bf16, 5.12 MB)
  //            | w2f (16 KB) | idx2 (4 MB)  => ~14.3 MB
  unsigned short* Pb  = (unsigned short*)d_ws;
  unsigned short* P1b = Pb;
  unsigned short* P2b = Pb + (size_t)NODES * H;
  unsigned short* Pgb = Pb + (size_t)2 * NODES * H;
  unsigned short* w2f = Pgb + (size_t)NGROUPS * H;
  int2* idx2 = (int2*)(w2f + 16 * 64 * 8);

  k_pre<<<PRE_BLOCKS, 256, 0, stream>>>(indices, x, W1, b1, W2,
                                        Pb, Pgb, w2f, idx2);
  k_main<<<(N_ROWS + 4 * RPW - 1) / (4 * RPW), 256, 0, stream>>>(
      idx2, P1b, P2b, Pgb, w2f, b2, W3, b3, out);
}